// Round 13
// baseline (637.963 us; speedup 1.0000x reference)
//
#include <hip/hip_runtime.h>
#include <stdint.h>

#define N_NODES 131072
#define N_EDGES 2097152
#define NG 64
#define HD 128
#define NL 3
#define EPSB 1e-5f

#define BUCKETS 256
#define BSHIFT 9               // 512 rows per bucket
#define ROWS_PB 512
#define CHUNK 8192             // edges per phase-A workgroup
#define NCHUNK (N_EDGES / CHUNK)   // 256
#define PAD_SLACK (7 * ROWS_PB)    // max pad8 slack per bucket = 3584
#define CSR_CAP (N_EDGES + BUCKETS * (PAD_SLACK + 8))
#define TPAD 68                // dword stride of per-wave LDS tile (16B aligned, 2-way banks)
#define PPAD 132               // dword stride of pool staging view (2-way banks)
#define NSHARD 8

typedef unsigned short ushort_t;
typedef __bf16 bf16x8 __attribute__((ext_vector_type(8)));
typedef float f32x4 __attribute__((ext_vector_type(4)));

__device__ __forceinline__ float bf2f(uint32_t u16) {
    union { uint32_t i; float f; } c; c.i = u16 << 16; return c.f;
}
__device__ __forceinline__ float lo2f(uint32_t u) {
    union { uint32_t i; float f; } c; c.i = u << 16; return c.f;
}
__device__ __forceinline__ float hi2f(uint32_t u) {
    union { uint32_t i; float f; } c; c.i = u & 0xffff0000u; return c.f;
}
__device__ __forceinline__ ushort_t f2bf(float f) {
    union { float f; uint32_t i; } c; c.f = f;
    uint32_t u = c.i;
    uint32_t r = (u + 0x7fffu + ((u >> 16) & 1u)) >> 16;
    return (ushort_t)r;
}
// dtype-adaptive scalar load: isb=1 -> bf16 array, isb=0 -> fp32 array
__device__ __forceinline__ float ldf(const void* p, int i, int isb) {
    return isb ? bf2f(((const ushort_t*)p)[i]) : ((const float*)p)[i];
}

// ---------------- dtype sniffer on edge_attr_raw
__global__ void detect_k(const uint32_t* __restrict__ ea, int* __restrict__ flag) {
    __shared__ int sm[256];
    int t = threadIdx.x;
    int plaus = 0;
    for (int j = 0; j < 16; j++) {
        uint32_t w = ea[t * 16 + j];
        uint32_t e0 = (w >> 7) & 0xFF;
        uint32_t e1 = (w >> 23) & 0xFF;
        plaus += (e0 >= 100 && e0 <= 140) ? 1 : 0;
        plaus += (e1 >= 100 && e1 <= 140) ? 1 : 0;
    }
    sm[t] = plaus;
    __syncthreads();
    for (int o = 128; o > 0; o >>= 1) {
        if (t < o) sm[t] += sm[t + o];
        __syncthreads();
    }
    if (t == 0) flag[0] = (sm[0] * 10 >= 8192 * 9) ? 1 : 0;
}

// ---------------- merged BN-fold + W_gcn transpose (block 0 also does BN fold)
__global__ void prep_transpose_k(
    const void* gamma, const void* beta, const void* mean, const void* var,
    const void* bgcn, float* sc, float* sh,
    const void* __restrict__ W, ushort_t* __restrict__ WTg,
    const int* __restrict__ flag)
{
    int isb = flag[0];
    int tid = threadIdx.x;
    if (blockIdx.x == 0) {
        for (int i = tid; i < NL * HD; i += 256) {
            float g = ldf(gamma, i, isb), b = ldf(beta, i, isb);
            float m = ldf(mean, i, isb), v = ldf(var, i, isb), bb = ldf(bgcn, i, isb);
            float s = g / sqrtf(v + EPSB);
            sc[i] = s;
            sh[i] = (bb - m) * s + b;
        }
    }
    int idx = blockIdx.x * 256 + tid;
    if (idx < NL * HD * HD) {
        int l = idx >> 14;
        int rem = idx & 16383;
        int k = rem >> 7, n = rem & 127;
        WTg[l * 16384 + n * 128 + k] = f2bf(ldf(W, idx, isb));
    }
}

// ---------------- degree histogram (global atomics; proven cheap in round 3).
// Produces deg[] with values identical to buildB's old per-bucket hist pass.
__global__ __launch_bounds__(256) void degcount_k(const int* __restrict__ row,
                                                  int* __restrict__ deg) {
    int t = blockIdx.x * 256 + threadIdx.x;
#pragma unroll
    for (int j = 0; j < 4; j++) {
        atomicAdd(&deg[row[t + j * 524288]], 1);
    }
}

// ---------------- Phase A: per-chunk bucket partition. 1024 threads/block.
// row/col/ea all register-carried between passes: pass 2 is global-read-free.
__global__ __launch_bounds__(1024) void bucketA_k(
    const int* __restrict__ row, const int* __restrict__ col,
    const void* __restrict__ ea_raw,
    uint2* __restrict__ staged, uint32_t* __restrict__ cntmat,
    uint32_t* __restrict__ offmat, const int* __restrict__ flag)
{
    __shared__ int hist[256], offs[256], offs_ex[256], cur[256];
    int isb = flag[0];
    int t = threadIdx.x;
    int base = blockIdx.x * CHUNK;
    int rr[CHUNK / 1024];
    uint32_t ck[CHUNK / 1024];
    uint32_t pk[CHUNK / 1024];
    if (t < 256) hist[t] = 0;
    __syncthreads();
#pragma unroll
    for (int j = 0; j < CHUNK / 1024; j++) {
        int e = base + j * 1024 + t;
        rr[j] = row[e];
        ck[j] = (uint32_t)col[e];
        if (isb) {
            pk[j] = ((const uint32_t*)ea_raw)[e];
        } else {
            const float* f = (const float*)ea_raw + (size_t)e * 2;
            pk[j] = (uint32_t)f2bf(f[0]) | ((uint32_t)f2bf(f[1]) << 16);
        }
        atomicAdd(&hist[rr[j] >> BSHIFT], 1);
    }
    __syncthreads();
    int v = 0;
    if (t < 256) { v = hist[t]; offs[t] = v; }
    __syncthreads();
    for (int o = 1; o < 256; o <<= 1) {
        int u = 0;
        if (t < 256 && t >= o) u = offs[t - o];
        __syncthreads();
        if (t < 256) offs[t] += u;
        __syncthreads();
    }
    if (t < 256) {
        offs_ex[t] = offs[t] - v;
        cur[t] = 0;
        cntmat[blockIdx.x * 256 + t] = (uint32_t)v;
        offmat[blockIdx.x * 256 + t] = (uint32_t)(offs[t] - v);
    }
    __syncthreads();
    uint2* slice = staged + (size_t)blockIdx.x * CHUNK;
#pragma unroll
    for (int j = 0; j < CHUNK / 1024; j++) {
        int r = rr[j];
        int b = r >> BSHIFT;
        int pos = offs_ex[b] + atomicAdd(&cur[b], 1);
        slice[pos] = make_uint2((uint32_t)(((r & (ROWS_PB - 1)) << 17) | ck[j]), pk[j]);
    }
}

// ---------------- merged bucket totals + pad8 scan (1 block).
__global__ __launch_bounds__(256) void bsumscan_k(const uint32_t* __restrict__ cntmat,
                                                  uint32_t* __restrict__ bbase) {
    __shared__ int sm[256];
    int t = threadIdx.x;
    int s = 0;
    for (int i = 0; i < 256; i++) s += (int)cntmat[i * 256 + t];
    int v = (s + PAD_SLACK + 7) & ~7;
    sm[t] = v;
    __syncthreads();
    for (int o = 1; o < 256; o <<= 1) {
        int u = (t >= o) ? sm[t - o] : 0;
        __syncthreads();
        sm[t] += u;
        __syncthreads();
    }
    bbase[t] = (uint32_t)(sm[t] - v);
}

// ---------------- Phase B v2: histogram pass DELETED — per-row degrees come
// from degcount_k's deg[] (identical integer values), so the pad8 po scan and
// csr_off are bit-identical to the old two-pass version. Single scatter pass
// over staged (4-way batched binary searches).
__global__ __launch_bounds__(1024) void buildB_k(
    const uint2* __restrict__ staged, const uint32_t* __restrict__ cntmat,
    const uint32_t* __restrict__ offmat, const uint32_t* __restrict__ bbase,
    const int* __restrict__ degv,
    uint2* __restrict__ csr, int* __restrict__ csr_off)
{
    __shared__ int runoff[257];
    __shared__ int runstart[256];
    __shared__ int po[512];
    __shared__ int cur2[512];
    int b = blockIdx.x, t = threadIdx.x;

    int myc = 0;
    if (t < 256) {
        myc = (int)cntmat[t * 256 + b];
        runstart[t] = t * CHUNK + (int)offmat[t * 256 + b];
        runoff[t] = myc;
    }
    int dgv = 0;
    if (t < 512) { dgv = degv[b * ROWS_PB + t]; cur2[t] = 0; }
    __syncthreads();
    for (int o = 1; o < 256; o <<= 1) {
        int u = 0;
        if (t < 256 && t >= o) u = runoff[t - o];
        __syncthreads();
        if (t < 256) runoff[t] += u;
        __syncthreads();
    }
    if (t < 256) {
        int incl = runoff[t];
        runoff[t] = incl - myc;
        if (t == 255) runoff[256] = incl;
    }
    __syncthreads();
    int T = runoff[256];

    int pv = 0;
    if (t < 512) { pv = (dgv + 7) & ~7; po[t] = pv; }
    __syncthreads();
    for (int o = 1; o < 512; o <<= 1) {
        int u = 0;
        if (t < 512 && t >= o) u = po[t - o];
        __syncthreads();
        if (t < 512) po[t] += u;
        __syncthreads();
    }
    if (t < 512) po[t] -= pv;
    __syncthreads();

    int gbase = (int)bbase[b];
    if (t < 512) csr_off[b * ROWS_PB + t] = gbase + po[t];

    int i = t;
    for (; i + 3072 < T; i += 4096) {
        int i0 = i, i1 = i + 1024, i2 = i + 2048, i3 = i + 3072;
        int lo0 = 0, hi0 = 255, lo1 = 0, hi1 = 255;
        int lo2 = 0, hi2 = 255, lo3 = 0, hi3 = 255;
#pragma unroll
        for (int s = 0; s < 8; s++) {
            int m0 = (lo0 + hi0 + 1) >> 1; if (runoff[m0] <= i0) lo0 = m0; else hi0 = m0 - 1;
            int m1 = (lo1 + hi1 + 1) >> 1; if (runoff[m1] <= i1) lo1 = m1; else hi1 = m1 - 1;
            int m2 = (lo2 + hi2 + 1) >> 1; if (runoff[m2] <= i2) lo2 = m2; else hi2 = m2 - 1;
            int m3 = (lo3 + hi3 + 1) >> 1; if (runoff[m3] <= i3) lo3 = m3; else hi3 = m3 - 1;
        }
        uint2 e0 = staged[runstart[lo0] + (i0 - runoff[lo0])];
        uint2 e1 = staged[runstart[lo1] + (i1 - runoff[lo1])];
        uint2 e2 = staged[runstart[lo2] + (i2 - runoff[lo2])];
        uint2 e3 = staged[runstart[lo3] + (i3 - runoff[lo3])];
        int r0 = e0.x >> 17, r1 = e1.x >> 17, r2 = e2.x >> 17, r3 = e3.x >> 17;
        int p0 = po[r0] + atomicAdd(&cur2[r0], 1);
        int p1 = po[r1] + atomicAdd(&cur2[r1], 1);
        int p2 = po[r2] + atomicAdd(&cur2[r2], 1);
        int p3 = po[r3] + atomicAdd(&cur2[r3], 1);
        csr[gbase + p0] = make_uint2(e0.x & 0x1FFFFu, e0.y);
        csr[gbase + p1] = make_uint2(e1.x & 0x1FFFFu, e1.y);
        csr[gbase + p2] = make_uint2(e2.x & 0x1FFFFu, e2.y);
        csr[gbase + p3] = make_uint2(e3.x & 0x1FFFFu, e3.y);
    }
    for (; i < T; i += 1024) {
        int lo = 0, hi = 255;
        while (lo < hi) { int mid = (lo + hi + 1) >> 1; if (runoff[mid] <= i) lo = mid; else hi = mid - 1; }
        uint2 en = staged[runstart[lo] + (i - runoff[lo])];
        int r = en.x >> 17;
        int pos = po[r] + atomicAdd(&cur2[r], 1);
        csr[gbase + pos] = make_uint2(en.x & 0x1FFFFu, en.y);
    }
    __syncthreads();
    if (t < 512) {
        int d = dgv, p = (d + 7) & ~7;
        for (int k = d; k < p; k++) csr[gbase + po[t] + k] = make_uint2(N_NODES, 0u);
    }
}

// ---------------- fused layer: ONE WAVE per block, 16 nodes, barrier-free.
// Round-10 configuration (best measured): PPAD pool-staging tile, shfl
// fast path for single-segment blocks, gsum sharded 8x. The dopool
// dispatch's +20us vs a non-pool layer survived 3 targeted fixes
// (atomics, epilogue work, LDS/occupancy) — accepted as unexplained.
__global__ __launch_bounds__(64, 4) void layer_fused_k(
    const uint32_t* __restrict__ h32,      // [N+1,64] u32 (bf16x2), row N zeroed
    const int* __restrict__ csr_off, const int* __restrict__ degv,
    const uint2* __restrict__ csr,
    const void* __restrict__ Wedge, const void* __restrict__ bedge,
    const ushort_t* __restrict__ WTg,      // [128][128] bf16, WT[n][k]
    const float* __restrict__ sc, const float* __restrict__ sh,
    ushort_t* __restrict__ Hout,           // [N+1][128] bf16
    float* __restrict__ gsum, float* __restrict__ gsum2,
    int* __restrict__ gcnt,
    const int* __restrict__ batch, int dopool,
    const int* __restrict__ flag)
{
    __shared__ uint32_t tile[16 * PPAD];   // tile phase uses stride TPAD; pool slow path stride PPAD
    int isb = flag[0];
    int lane = threadIdx.x;
    int quad = lane >> 4, l16 = lane & 15;
    int nodebase = blockIdx.x * 16;

    float w0x = ldf(Wedge, 2 * lane, isb),       w0y = ldf(Wedge, 2 * lane + 1, isb);
    float w1x = ldf(Wedge, 128 + 2 * lane, isb), w1y = ldf(Wedge, 128 + 2 * lane + 1, isb);
    float bex = ldf(bedge, 2 * lane, isb),       bey = ldf(bedge, 2 * lane + 1, isb);

    int dg = degv[nodebase];
    int st = csr_off[nodebase];
    for (int i = 0; i < 16; i++) {
        int dgn = 0, stn = 0;
        if (i < 15) {                       // prefetch next node's meta
            dgn = degv[nodebase + i + 1];
            stn = csr_off[nodebase + i + 1];
        }
        uint32_t hn = h32[(uint32_t)(nodebase + i) * 64 + lane];  // own row, early

        int nit = (dg + 7) >> 3;
        const uint4* gp = (const uint4*)csr + (st >> 1);
        float ax = 0.f, ay = 0.f;
        int it = 0;
        for (; it + 2 <= nit; it += 2) {   // 16 gathers in flight
            uint4 q0 = gp[0], q1 = gp[1], q2 = gp[2], q3 = gp[3];
            uint4 q4 = gp[4], q5 = gp[5], q6 = gp[6], q7 = gp[7];
            gp += 8;
            uint32_t cols[16] = {q0.x, q0.z, q1.x, q1.z, q2.x, q2.z, q3.x, q3.z,
                                 q4.x, q4.z, q5.x, q5.z, q6.x, q6.z, q7.x, q7.z};
            uint32_t eav[16]  = {q0.y, q0.w, q1.y, q1.w, q2.y, q2.w, q3.y, q3.w,
                                 q4.y, q4.w, q5.y, q5.w, q6.y, q6.w, q7.y, q7.w};
            uint32_t hv[16];
#pragma unroll
            for (int j = 0; j < 16; j++) hv[j] = h32[cols[j] * 64 + lane];
#pragma unroll
            for (int j = 0; j < 16; j++) {
                float a0 = bf2f(eav[j] & 0xffffu);
                float a1 = bf2f(eav[j] >> 16);
                float ex = fmaf(a1, w1x, fmaf(a0, w0x, bex));
                float ey = fmaf(a1, w1y, fmaf(a0, w0y, bey));
                ax = fmaf(lo2f(hv[j]), ex, ax);
                ay = fmaf(hi2f(hv[j]), ey, ay);
            }
        }
        if (it < nit) {                    // tail group of 8
            uint4 q0 = gp[0], q1 = gp[1], q2 = gp[2], q3 = gp[3];
            uint32_t cols[8] = {q0.x, q0.z, q1.x, q1.z, q2.x, q2.z, q3.x, q3.z};
            uint32_t eav[8]  = {q0.y, q0.w, q1.y, q1.w, q2.y, q2.w, q3.y, q3.w};
            uint32_t hv[8];
#pragma unroll
            for (int j = 0; j < 8; j++) hv[j] = h32[cols[j] * 64 + lane];
#pragma unroll
            for (int j = 0; j < 8; j++) {
                float a0 = bf2f(eav[j] & 0xffffu);
                float a1 = bf2f(eav[j] >> 16);
                float ex = fmaf(a1, w1x, fmaf(a0, w0x, bex));
                float ey = fmaf(a1, w1y, fmaf(a0, w0y, bey));
                ax = fmaf(lo2f(hv[j]), ex, ax);
                ay = fmaf(hi2f(hv[j]), ey, ay);
            }
        }
        float inv = 1.0f / (float)(dg > 0 ? dg : 1);
        float tx = lo2f(hn) + ax * inv;
        float ty = hi2f(hn) + ay * inv;
        tile[i * TPAD + lane] = (uint32_t)f2bf(tx) | ((uint32_t)f2bf(ty) << 16);
        dg = dgn; st = stn;
    }
    // no barrier: single wave, own tile

    f32x4 acc[8];
#pragma unroll
    for (int c = 0; c < 8; c++) acc[c] = (f32x4){0.f, 0.f, 0.f, 0.f};

#pragma unroll
    for (int kk = 0; kk < 4; kk++) {
        bf16x8 a = *(const bf16x8*)(tile + l16 * TPAD + kk * 16 + quad * 4);
#pragma unroll
        for (int c = 0; c < 8; c++) {
            bf16x8 b = *(const bf16x8*)(WTg + (c * 16 + l16) * 128 + kk * 32 + quad * 8);
            acc[c] = __builtin_amdgcn_mfma_f32_16x16x32_bf16(a, b, acc[c], 0, 0, 0);
        }
    }
    if (!dopool) {
#pragma unroll
        for (int c = 0; c < 8; c++) {
            int gcol = c * 16 + l16;
            float s = sc[gcol], o = sh[gcol];
#pragma unroll
            for (int r = 0; r < 4; r++) {
                float v = fmaxf(fmaf(acc[c][r], s, o), 0.f);
                Hout[(size_t)(nodebase + quad * 4 + r) * 128 + gcol] = f2bf(v);
            }
        }
    } else {
        int shard = blockIdx.x & (NSHARD - 1);
        float* gs = (shard == 0) ? gsum : (gsum2 + (size_t)(shard - 1) * NG * HD);
        int bg0 = batch[nodebase];
        int bg15 = batch[nodebase + 15];
        if (bg0 == bg15) {
            // fast path: whole tile in one segment; register column-sums +
            // cross-quad shfl reduce; one atomic per column from quad 0.
#pragma unroll
            for (int c = 0; c < 8; c++) {
                int gcol = c * 16 + l16;
                float s = sc[gcol], o = sh[gcol];
                float cs = 0.f;
#pragma unroll
                for (int r = 0; r < 4; r++) {
                    float v = fmaxf(fmaf(acc[c][r], s, o), 0.f);
                    cs += bf2f(f2bf(v));
                }
                cs += __shfl_xor(cs, 16);
                cs += __shfl_xor(cs, 32);
                if (quad == 0) atomicAdd(&gs[bg0 * 128 + gcol], cs);
            }
            if (lane == 0) atomicAdd(&gcnt[bg0], 16);
        } else {
            // slow path (segment boundary): LDS staging + segment scan
#pragma unroll
            for (int c = 0; c < 8; c++) {
                int gcol = c * 16 + l16;
                float s = sc[gcol], o = sh[gcol];
#pragma unroll
                for (int r = 0; r < 4; r++) {
                    float v = fmaxf(fmaf(acc[c][r], s, o), 0.f);
                    float vb = bf2f(f2bf(v));
                    tile[(quad * 4 + r) * PPAD + gcol] = __float_as_uint(vb);
                }
            }
            int bg[16];
#pragma unroll
            for (int i = 0; i < 16; i++) bg[i] = batch[nodebase + i];
#pragma unroll
            for (int cc = 0; cc < 2; cc++) {
                int colx = lane + cc * 64;
                float s = 0.f;
                int g = bg[0];
#pragma unroll
                for (int i = 0; i < 16; i++) {
                    int gi = bg[i];
                    if (gi != g) { atomicAdd(&gs[g * 128 + colx], s); s = 0.f; g = gi; }
                    s += __uint_as_float(tile[i * PPAD + colx]);
                }
                atomicAdd(&gs[g * 128 + colx], s);
            }
            if (lane == 0) {
                int g = bg[0]; int c = 0;
#pragma unroll
                for (int i = 0; i < 16; i++) {
                    int gi = bg[i];
                    if (gi != g) { atomicAdd(&gcnt[g], c); c = 0; g = gi; }
                    c++;
                }
                atomicAdd(&gcnt[g], c);
            }
        }
    }
}

// ---------------- GEMM: h0 = x @ W_in + b_in   ([N,64]x[64,128]) -> internal bf16
// Block 0 additionally zeroes the dummy row N of both hA and hB (replaces
// two 256B memset dispatches; runs before any layer reads them).
__global__ __launch_bounds__(256) void gemm_in_k(
    const void* __restrict__ X, const void* __restrict__ W,
    const void* __restrict__ bin, ushort_t* __restrict__ Hout,
    ushort_t* __restrict__ HoutB, const int* __restrict__ flag)
{
    __shared__ ushort_t WT[128 * 72];
    int isb = flag[0];
    int tid = threadIdx.x;
    if (blockIdx.x == 0 && tid < 64) {
        ((uint32_t*)(Hout + (size_t)N_NODES * HD))[tid] = 0u;
        ((uint32_t*)(HoutB + (size_t)N_NODES * HD))[tid] = 0u;
    }
    for (int idx = tid; idx < 64 * 128; idx += 256) {
        int k = idx >> 7, n = idx & 127;
        WT[n * 72 + k] = f2bf(ldf(W, idx, isb));
    }
    __syncthreads();
    int wave = tid >> 6, lane = tid & 63;
    int quad = lane >> 4, l16 = lane & 15;
    int row = blockIdx.x * 64 + wave * 16 + l16;

    f32x4 acc[8];
#pragma unroll
    for (int c = 0; c < 8; c++) acc[c] = (f32x4){0.f, 0.f, 0.f, 0.f};

#pragma unroll
    for (int kk = 0; kk < 2; kk++) {
        int aoff = row * 64 + kk * 32 + quad * 8;
        union { bf16x8 v; ushort_t s[8]; } a;
        if (isb) {
            a.v = *(const bf16x8*)((const ushort_t*)X + aoff);
        } else {
            const float* xf = (const float*)X + aoff;
            f32x4 p0 = *(const f32x4*)xf;
            f32x4 p1 = *(const f32x4*)(xf + 4);
#pragma unroll
            for (int j = 0; j < 4; j++) { a.s[j] = f2bf(p0[j]); a.s[4 + j] = f2bf(p1[j]); }
        }
#pragma unroll
        for (int c = 0; c < 8; c++) {
            bf16x8 b = *(const bf16x8*)(&WT[(c * 16 + l16) * 72 + kk * 32 + quad * 8]);
            acc[c] = __builtin_amdgcn_mfma_f32_16x16x32_bf16(a.v, b, acc[c], 0, 0, 0);
        }
    }
    int rbase = blockIdx.x * 64 + wave * 16 + quad * 4;
#pragma unroll
    for (int c = 0; c < 8; c++) {
        int gcol = c * 16 + l16;
        float bb = ldf(bin, gcol, isb);
#pragma unroll
        for (int r = 0; r < 4; r++) {
            Hout[(rbase + r) * 128 + gcol] = f2bf(acc[c][r] + bb);
        }
    }
}

// ---------------- final: sums the 8 gsum shards
__global__ __launch_bounds__(128) void final_k(
    const float* __restrict__ gsum, const float* __restrict__ gsum2,
    const int* __restrict__ gcnt,
    const void* __restrict__ gx, const void* __restrict__ Wgp,
    const void* __restrict__ bgp, const void* __restrict__ Wgc,
    const void* __restrict__ bgc, void* __restrict__ out,
    const int* __restrict__ flag)
{
    __shared__ float gm[160];
    int isb = flag[0];
    int g = blockIdx.x, t = threadIdx.x;
    int c = gcnt[g]; if (c < 1) c = 1;
    float acc = gsum[g * 128 + t];
#pragma unroll
    for (int s = 1; s < NSHARD; s++)
        acc += gsum2[(size_t)(s - 1) * NG * HD + g * 128 + t];
    gm[t] = acc / (float)c;
    if (t < 32) {
        float a = ldf(bgp, t, isb);
        for (int d = 0; d < 6; d++) a += ldf(gx, g * 6 + d, isb) * ldf(Wgp, d * 32 + t, isb);
        gm[128 + t] = fmaxf(a, 0.f);
    }
    __syncthreads();
    float a = ldf(bgc, t, isb);
    for (int k = 0; k < 160; k++) a += gm[k] * ldf(Wgc, k * 128 + t, isb);
    if (isb) ((ushort_t*)out)[g * 128 + t] = f2bf(a);
    else     ((float*)out)[g * 128 + t] = a;
}

extern "C" void kernel_launch(void* const* d_in, const int* in_sizes, int n_in,
                              void* d_out, int out_size, void* d_ws, size_t ws_size,
                              hipStream_t stream) {
    const void* x       = d_in[0];
    const void* ea_raw  = d_in[1];
    const void* gx      = d_in[2];
    const void* W_in    = d_in[3];
    const void* b_in    = d_in[4];
    const void* W_edge  = d_in[5];
    const void* b_edge  = d_in[6];
    const void* W_gcn   = d_in[7];
    const void* b_gcn   = d_in[8];
    const void* bn_g    = d_in[9];
    const void* bn_b    = d_in[10];
    const void* bn_m    = d_in[11];
    const void* bn_v    = d_in[12];
    const void* W_gproj = d_in[13];
    const void* b_gproj = d_in[14];
    const void* W_gcomb = d_in[15];
    const void* b_gcomb = d_in[16];
    const int* row   = (const int*)d_in[17];
    const int* col   = (const int*)d_in[18];
    const int* batch = (const int*)d_in[19];

    char* ws = (char*)d_ws;
    size_t off = 0;
    float*    gsum    = (float*)(ws + off);    off += (size_t)NG * HD * 4;
    int*      gcnt    = (int*)(ws + off);      off += 256;
    size_t zero_bytes = off;                    // [gsum|gcnt]
    int*      flag    = (int*)(ws + off);      off += 256;
    uint32_t* cntmat  = (uint32_t*)(ws + off); off += 256 * 256 * 4;
    uint32_t* offmat  = (uint32_t*)(ws + off); off += 256 * 256 * 4;
    uint32_t* btot    = (uint32_t*)(ws + off); off += 1024;   // slot retained (layout frozen); unused
    uint32_t* bbase   = (uint32_t*)(ws + off); off += 1024;
    int*      csr_off = (int*)(ws + off);      off += (size_t)N_NODES * 4;
    int*      deg     = (int*)(ws + off);      off += (size_t)N_NODES * 4;
    ushort_t* wtg     = (ushort_t*)(ws + off); off += (size_t)NL * HD * HD * 2;
    float*    sc      = (float*)(ws + off);    off += (size_t)NL * HD * 4;
    float*    sh      = (float*)(ws + off);    off += (size_t)NL * HD * 4;
    uint2*    csr     = (uint2*)(ws + off);    off += (size_t)CSR_CAP * 8;
    ushort_t* hA      = (ushort_t*)(ws + off); off += (size_t)(N_NODES + 1) * HD * 2;
    ushort_t* hB      = (ushort_t*)(ws + off); off += (size_t)(N_NODES + 1) * HD * 2;
    uint2*    staged  = (uint2*)hB;  // overlay: staged (16.8MB) dead before layer0 writes hB
    // overlay: gsum shards 1..7 (224KB) on cntmat (256KB), dead after buildB
    float*    gsum2   = (float*)cntmat;
    (void)btot;

    hipMemsetAsync(ws, 0, zero_bytes, stream);
    hipMemsetAsync(deg, 0, (size_t)N_NODES * 4, stream);
    detect_k<<<1, 256, 0, stream>>>((const uint32_t*)ea_raw, flag);
    prep_transpose_k<<<(NL * HD * HD + 255) / 256, 256, 0, stream>>>(
        bn_g, bn_b, bn_m, bn_v, b_gcn, sc, sh, W_gcn, wtg, flag);

    degcount_k<<<2048, 256, 0, stream>>>(row, deg);
    bucketA_k<<<NCHUNK, 1024, 0, stream>>>(row, col, ea_raw, staged, cntmat, offmat, flag);
    bsumscan_k<<<1, 256, 0, stream>>>(cntmat, bbase);
    buildB_k<<<BUCKETS, 1024, 0, stream>>>(staged, cntmat, offmat, bbase, deg, csr, csr_off);
    // cntmat dead; zero the shard overlay before the pooling layer runs
    hipMemsetAsync(gsum2, 0, (size_t)(NSHARD - 1) * NG * HD * 4, stream);

    gemm_in_k<<<N_NODES / 64, 256, 0, stream>>>(x, W_in, b_in, hA, hB, flag);

    ushort_t* hin = hA;
    ushort_t* hout = hB;
    for (int l = 0; l < NL; l++) {
        layer_fused_k<<<N_NODES / 16, 64, 0, stream>>>(
            (const uint32_t*)hin, csr_off, deg, csr,
            W_edge, b_edge, wtg + (size_t)l * HD * HD, sc + l * HD, sh + l * HD,
            hout, gsum, gsum2, gcnt, batch, (l == NL - 1) ? 1 : 0, flag);
        ushort_t* tmp = hin; hin = hout; hout = tmp;
    }

    final_k<<<NG, 128, 0, stream>>>(gsum, gsum2, gcnt, gx, W_gproj, b_gproj,
                                    W_gcomb, b_gcomb, d_out, flag);
}

// Round 14
// 551.527 us; speedup vs baseline: 1.1567x; 1.1567x over previous
//
#include <hip/hip_runtime.h>
#include <stdint.h>

#define N_NODES 131072
#define N_EDGES 2097152
#define NG 64
#define HD 128
#define NL 3
#define EPSB 1e-5f

#define BUCKETS 256
#define BSHIFT 9               // 512 rows per bucket
#define ROWS_PB 512
#define CHUNK 8192             // edges per phase-A workgroup
#define NCHUNK (N_EDGES / CHUNK)   // 256
#define PAD_SLACK (7 * ROWS_PB)    // max pad8 slack per bucket = 3584
#define CSR_CAP (N_EDGES + BUCKETS * (PAD_SLACK + 8))
#define TPAD 68                // dword stride of per-wave LDS tile (16B aligned, 2-way banks)
#define PPAD 132               // dword stride of pool staging view (2-way banks)
#define NSHARD 8

typedef unsigned short ushort_t;
typedef __bf16 bf16x8 __attribute__((ext_vector_type(8)));
typedef float f32x4 __attribute__((ext_vector_type(4)));

__device__ __forceinline__ float bf2f(uint32_t u16) {
    union { uint32_t i; float f; } c; c.i = u16 << 16; return c.f;
}
__device__ __forceinline__ float lo2f(uint32_t u) {
    union { uint32_t i; float f; } c; c.i = u << 16; return c.f;
}
__device__ __forceinline__ float hi2f(uint32_t u) {
    union { uint32_t i; float f; } c; c.i = u & 0xffff0000u; return c.f;
}
__device__ __forceinline__ ushort_t f2bf(float f) {
    union { float f; uint32_t i; } c; c.f = f;
    uint32_t u = c.i;
    uint32_t r = (u + 0x7fffu + ((u >> 16) & 1u)) >> 16;
    return (ushort_t)r;
}
// dtype-adaptive scalar load: isb=1 -> bf16 array, isb=0 -> fp32 array
__device__ __forceinline__ float ldf(const void* p, int i, int isb) {
    return isb ? bf2f(((const ushort_t*)p)[i]) : ((const float*)p)[i];
}

// ---------------- dtype sniffer on edge_attr_raw
__global__ void detect_k(const uint32_t* __restrict__ ea, int* __restrict__ flag) {
    __shared__ int sm[256];
    int t = threadIdx.x;
    int plaus = 0;
    for (int j = 0; j < 16; j++) {
        uint32_t w = ea[t * 16 + j];
        uint32_t e0 = (w >> 7) & 0xFF;
        uint32_t e1 = (w >> 23) & 0xFF;
        plaus += (e0 >= 100 && e0 <= 140) ? 1 : 0;
        plaus += (e1 >= 100 && e1 <= 140) ? 1 : 0;
    }
    sm[t] = plaus;
    __syncthreads();
    for (int o = 128; o > 0; o >>= 1) {
        if (t < o) sm[t] += sm[t + o];
        __syncthreads();
    }
    if (t == 0) flag[0] = (sm[0] * 10 >= 8192 * 9) ? 1 : 0;
}

// ---------------- merged BN-fold + W_gcn transpose (block 0 also does BN fold)
__global__ void prep_transpose_k(
    const void* gamma, const void* beta, const void* mean, const void* var,
    const void* bgcn, float* sc, float* sh,
    const void* __restrict__ W, ushort_t* __restrict__ WTg,
    const int* __restrict__ flag)
{
    int isb = flag[0];
    int tid = threadIdx.x;
    if (blockIdx.x == 0) {
        for (int i = tid; i < NL * HD; i += 256) {
            float g = ldf(gamma, i, isb), b = ldf(beta, i, isb);
            float m = ldf(mean, i, isb), v = ldf(var, i, isb), bb = ldf(bgcn, i, isb);
            float s = g / sqrtf(v + EPSB);
            sc[i] = s;
            sh[i] = (bb - m) * s + b;
        }
    }
    int idx = blockIdx.x * 256 + tid;
    if (idx < NL * HD * HD) {
        int l = idx >> 14;
        int rem = idx & 16383;
        int k = rem >> 7, n = rem & 127;
        WTg[l * 16384 + n * 128 + k] = f2bf(ldf(W, idx, isb));
    }
}

// ---------------- Phase A: per-chunk bucket partition. 1024 threads/block.
// row/col/ea all register-carried between passes: pass 2 is global-read-free.
__global__ __launch_bounds__(1024) void bucketA_k(
    const int* __restrict__ row, const int* __restrict__ col,
    const void* __restrict__ ea_raw,
    uint2* __restrict__ staged, uint32_t* __restrict__ cntmat,
    uint32_t* __restrict__ offmat, const int* __restrict__ flag)
{
    __shared__ int hist[256], offs[256], offs_ex[256], cur[256];
    int isb = flag[0];
    int t = threadIdx.x;
    int base = blockIdx.x * CHUNK;
    int rr[CHUNK / 1024];
    uint32_t ck[CHUNK / 1024];
    uint32_t pk[CHUNK / 1024];
    if (t < 256) hist[t] = 0;
    __syncthreads();
#pragma unroll
    for (int j = 0; j < CHUNK / 1024; j++) {
        int e = base + j * 1024 + t;
        rr[j] = row[e];
        ck[j] = (uint32_t)col[e];
        if (isb) {
            pk[j] = ((const uint32_t*)ea_raw)[e];
        } else {
            const float* f = (const float*)ea_raw + (size_t)e * 2;
            pk[j] = (uint32_t)f2bf(f[0]) | ((uint32_t)f2bf(f[1]) << 16);
        }
        atomicAdd(&hist[rr[j] >> BSHIFT], 1);
    }
    __syncthreads();
    int v = 0;
    if (t < 256) { v = hist[t]; offs[t] = v; }
    __syncthreads();
    for (int o = 1; o < 256; o <<= 1) {
        int u = 0;
        if (t < 256 && t >= o) u = offs[t - o];
        __syncthreads();
        if (t < 256) offs[t] += u;
        __syncthreads();
    }
    if (t < 256) {
        offs_ex[t] = offs[t] - v;
        cur[t] = 0;
        cntmat[blockIdx.x * 256 + t] = (uint32_t)v;
        offmat[blockIdx.x * 256 + t] = (uint32_t)(offs[t] - v);
    }
    __syncthreads();
    uint2* slice = staged + (size_t)blockIdx.x * CHUNK;
#pragma unroll
    for (int j = 0; j < CHUNK / 1024; j++) {
        int r = rr[j];
        int b = r >> BSHIFT;
        int pos = offs_ex[b] + atomicAdd(&cur[b], 1);
        slice[pos] = make_uint2((uint32_t)(((r & (ROWS_PB - 1)) << 17) | ck[j]), pk[j]);
    }
}

// ---------------- merged bucket totals + pad8 scan (1 block).
// Thread t sums column t of cntmat (coalesced per iteration), then LDS scan.
// Integer sums: bit-identical to the old bucketsum_k + scan2_k pair.
__global__ __launch_bounds__(256) void bsumscan_k(const uint32_t* __restrict__ cntmat,
                                                  uint32_t* __restrict__ bbase) {
    __shared__ int sm[256];
    int t = threadIdx.x;
    int s = 0;
    for (int i = 0; i < 256; i++) s += (int)cntmat[i * 256 + t];
    int v = (s + PAD_SLACK + 7) & ~7;
    sm[t] = v;
    __syncthreads();
    for (int o = 1; o < 256; o <<= 1) {
        int u = (t >= o) ? sm[t - o] : 0;
        __syncthreads();
        sm[t] += u;
        __syncthreads();
    }
    bbase[t] = (uint32_t)(sm[t] - v);
}

// ---------------- Phase B: one bucket per WG. Element loops 4-way batched.
// Two passes over staged (hist + scatter) are kept deliberately: after
// bucketA, staged is L2-resident, so the hist pass is cheap AND warms L2
// for the scatter. (Round 13 falsified the degcount_k replacement: −83us.)
__global__ __launch_bounds__(1024) void buildB_k(
    const uint2* __restrict__ staged, const uint32_t* __restrict__ cntmat,
    const uint32_t* __restrict__ offmat, const uint32_t* __restrict__ bbase,
    uint2* __restrict__ csr, int* __restrict__ csr_off, int* __restrict__ deg)
{
    __shared__ int runoff[257];
    __shared__ int runstart[256];
    __shared__ int hist2[512];
    __shared__ int po[512];
    __shared__ int cur2[512];
    int b = blockIdx.x, t = threadIdx.x;

    int myc = 0;
    if (t < 256) {
        myc = (int)cntmat[t * 256 + b];
        runstart[t] = t * CHUNK + (int)offmat[t * 256 + b];
        runoff[t] = myc;
    }
    if (t < 512) { hist2[t] = 0; cur2[t] = 0; }
    __syncthreads();
    for (int o = 1; o < 256; o <<= 1) {
        int u = 0;
        if (t < 256 && t >= o) u = runoff[t - o];
        __syncthreads();
        if (t < 256) runoff[t] += u;
        __syncthreads();
    }
    if (t < 256) {
        int incl = runoff[t];
        runoff[t] = incl - myc;
        if (t == 255) runoff[256] = incl;
    }
    __syncthreads();
    int T = runoff[256];

    int i = t;
    for (; i + 3072 < T; i += 4096) {
        int i0 = i, i1 = i + 1024, i2 = i + 2048, i3 = i + 3072;
        int lo0 = 0, hi0 = 255, lo1 = 0, hi1 = 255;
        int lo2 = 0, hi2 = 255, lo3 = 0, hi3 = 255;
#pragma unroll
        for (int s = 0; s < 8; s++) {
            int m0 = (lo0 + hi0 + 1) >> 1; if (runoff[m0] <= i0) lo0 = m0; else hi0 = m0 - 1;
            int m1 = (lo1 + hi1 + 1) >> 1; if (runoff[m1] <= i1) lo1 = m1; else hi1 = m1 - 1;
            int m2 = (lo2 + hi2 + 1) >> 1; if (runoff[m2] <= i2) lo2 = m2; else hi2 = m2 - 1;
            int m3 = (lo3 + hi3 + 1) >> 1; if (runoff[m3] <= i3) lo3 = m3; else hi3 = m3 - 1;
        }
        uint32_t x0 = staged[runstart[lo0] + (i0 - runoff[lo0])].x;
        uint32_t x1 = staged[runstart[lo1] + (i1 - runoff[lo1])].x;
        uint32_t x2 = staged[runstart[lo2] + (i2 - runoff[lo2])].x;
        uint32_t x3 = staged[runstart[lo3] + (i3 - runoff[lo3])].x;
        atomicAdd(&hist2[x0 >> 17], 1);
        atomicAdd(&hist2[x1 >> 17], 1);
        atomicAdd(&hist2[x2 >> 17], 1);
        atomicAdd(&hist2[x3 >> 17], 1);
    }
    for (; i < T; i += 1024) {
        int lo = 0, hi = 255;
        while (lo < hi) { int mid = (lo + hi + 1) >> 1; if (runoff[mid] <= i) lo = mid; else hi = mid - 1; }
        uint32_t x = staged[runstart[lo] + (i - runoff[lo])].x;
        atomicAdd(&hist2[x >> 17], 1);
    }
    __syncthreads();

    int pv = 0;
    if (t < 512) { pv = (hist2[t] + 7) & ~7; po[t] = pv; }
    __syncthreads();
    for (int o = 1; o < 512; o <<= 1) {
        int u = 0;
        if (t < 512 && t >= o) u = po[t - o];
        __syncthreads();
        if (t < 512) po[t] += u;
        __syncthreads();
    }
    if (t < 512) po[t] -= pv;
    __syncthreads();

    int gbase = (int)bbase[b];
    if (t < 512) {
        csr_off[b * ROWS_PB + t] = gbase + po[t];
        deg[b * ROWS_PB + t] = hist2[t];
    }

    i = t;
    for (; i + 3072 < T; i += 4096) {
        int i0 = i, i1 = i + 1024, i2 = i + 2048, i3 = i + 3072;
        int lo0 = 0, hi0 = 255, lo1 = 0, hi1 = 255;
        int lo2 = 0, hi2 = 255, lo3 = 0, hi3 = 255;
#pragma unroll
        for (int s = 0; s < 8; s++) {
            int m0 = (lo0 + hi0 + 1) >> 1; if (runoff[m0] <= i0) lo0 = m0; else hi0 = m0 - 1;
            int m1 = (lo1 + hi1 + 1) >> 1; if (runoff[m1] <= i1) lo1 = m1; else hi1 = m1 - 1;
            int m2 = (lo2 + hi2 + 1) >> 1; if (runoff[m2] <= i2) lo2 = m2; else hi2 = m2 - 1;
            int m3 = (lo3 + hi3 + 1) >> 1; if (runoff[m3] <= i3) lo3 = m3; else hi3 = m3 - 1;
        }
        uint2 e0 = staged[runstart[lo0] + (i0 - runoff[lo0])];
        uint2 e1 = staged[runstart[lo1] + (i1 - runoff[lo1])];
        uint2 e2 = staged[runstart[lo2] + (i2 - runoff[lo2])];
        uint2 e3 = staged[runstart[lo3] + (i3 - runoff[lo3])];
        int r0 = e0.x >> 17, r1 = e1.x >> 17, r2 = e2.x >> 17, r3 = e3.x >> 17;
        int p0 = po[r0] + atomicAdd(&cur2[r0], 1);
        int p1 = po[r1] + atomicAdd(&cur2[r1], 1);
        int p2 = po[r2] + atomicAdd(&cur2[r2], 1);
        int p3 = po[r3] + atomicAdd(&cur2[r3], 1);
        csr[gbase + p0] = make_uint2(e0.x & 0x1FFFFu, e0.y);
        csr[gbase + p1] = make_uint2(e1.x & 0x1FFFFu, e1.y);
        csr[gbase + p2] = make_uint2(e2.x & 0x1FFFFu, e2.y);
        csr[gbase + p3] = make_uint2(e3.x & 0x1FFFFu, e3.y);
    }
    for (; i < T; i += 1024) {
        int lo = 0, hi = 255;
        while (lo < hi) { int mid = (lo + hi + 1) >> 1; if (runoff[mid] <= i) lo = mid; else hi = mid - 1; }
        uint2 en = staged[runstart[lo] + (i - runoff[lo])];
        int r = en.x >> 17;
        int pos = po[r] + atomicAdd(&cur2[r], 1);
        csr[gbase + pos] = make_uint2(en.x & 0x1FFFFu, en.y);
    }
    __syncthreads();
    if (t < 512) {
        int d = hist2[t], p = (d + 7) & ~7;
        for (int k = d; k < p; k++) csr[gbase + po[t] + k] = make_uint2(N_NODES, 0u);
    }
}

// ---------------- fused layer: ONE WAVE per block, 16 nodes, barrier-free.
// Round-10 configuration (best measured): PPAD pool-staging tile, shfl
// fast path for single-segment blocks, gsum sharded 8x. The dopool
// dispatch's +20us vs a non-pool layer survived 3 targeted fixes
// (atomics, epilogue work, LDS/occupancy) — accepted as unexplained.
__global__ __launch_bounds__(64, 4) void layer_fused_k(
    const uint32_t* __restrict__ h32,      // [N+1,64] u32 (bf16x2), row N zeroed
    const int* __restrict__ csr_off, const int* __restrict__ degv,
    const uint2* __restrict__ csr,
    const void* __restrict__ Wedge, const void* __restrict__ bedge,
    const ushort_t* __restrict__ WTg,      // [128][128] bf16, WT[n][k]
    const float* __restrict__ sc, const float* __restrict__ sh,
    ushort_t* __restrict__ Hout,           // [N+1][128] bf16
    float* __restrict__ gsum, float* __restrict__ gsum2,
    int* __restrict__ gcnt,
    const int* __restrict__ batch, int dopool,
    const int* __restrict__ flag)
{
    __shared__ uint32_t tile[16 * PPAD];   // tile phase uses stride TPAD; pool slow path stride PPAD
    int isb = flag[0];
    int lane = threadIdx.x;
    int quad = lane >> 4, l16 = lane & 15;
    int nodebase = blockIdx.x * 16;

    float w0x = ldf(Wedge, 2 * lane, isb),       w0y = ldf(Wedge, 2 * lane + 1, isb);
    float w1x = ldf(Wedge, 128 + 2 * lane, isb), w1y = ldf(Wedge, 128 + 2 * lane + 1, isb);
    float bex = ldf(bedge, 2 * lane, isb),       bey = ldf(bedge, 2 * lane + 1, isb);

    int dg = degv[nodebase];
    int st = csr_off[nodebase];
    for (int i = 0; i < 16; i++) {
        int dgn = 0, stn = 0;
        if (i < 15) {                       // prefetch next node's meta
            dgn = degv[nodebase + i + 1];
            stn = csr_off[nodebase + i + 1];
        }
        uint32_t hn = h32[(uint32_t)(nodebase + i) * 64 + lane];  // own row, early

        int nit = (dg + 7) >> 3;
        const uint4* gp = (const uint4*)csr + (st >> 1);
        float ax = 0.f, ay = 0.f;
        int it = 0;
        for (; it + 2 <= nit; it += 2) {   // 16 gathers in flight
            uint4 q0 = gp[0], q1 = gp[1], q2 = gp[2], q3 = gp[3];
            uint4 q4 = gp[4], q5 = gp[5], q6 = gp[6], q7 = gp[7];
            gp += 8;
            uint32_t cols[16] = {q0.x, q0.z, q1.x, q1.z, q2.x, q2.z, q3.x, q3.z,
                                 q4.x, q4.z, q5.x, q5.z, q6.x, q6.z, q7.x, q7.z};
            uint32_t eav[16]  = {q0.y, q0.w, q1.y, q1.w, q2.y, q2.w, q3.y, q3.w,
                                 q4.y, q4.w, q5.y, q5.w, q6.y, q6.w, q7.y, q7.w};
            uint32_t hv[16];
#pragma unroll
            for (int j = 0; j < 16; j++) hv[j] = h32[cols[j] * 64 + lane];
#pragma unroll
            for (int j = 0; j < 16; j++) {
                float a0 = bf2f(eav[j] & 0xffffu);
                float a1 = bf2f(eav[j] >> 16);
                float ex = fmaf(a1, w1x, fmaf(a0, w0x, bex));
                float ey = fmaf(a1, w1y, fmaf(a0, w0y, bey));
                ax = fmaf(lo2f(hv[j]), ex, ax);
                ay = fmaf(hi2f(hv[j]), ey, ay);
            }
        }
        if (it < nit) {                    // tail group of 8
            uint4 q0 = gp[0], q1 = gp[1], q2 = gp[2], q3 = gp[3];
            uint32_t cols[8] = {q0.x, q0.z, q1.x, q1.z, q2.x, q2.z, q3.x, q3.z};
            uint32_t eav[8]  = {q0.y, q0.w, q1.y, q1.w, q2.y, q2.w, q3.y, q3.w};
            uint32_t hv[8];
#pragma unroll
            for (int j = 0; j < 8; j++) hv[j] = h32[cols[j] * 64 + lane];
#pragma unroll
            for (int j = 0; j < 8; j++) {
                float a0 = bf2f(eav[j] & 0xffffu);
                float a1 = bf2f(eav[j] >> 16);
                float ex = fmaf(a1, w1x, fmaf(a0, w0x, bex));
                float ey = fmaf(a1, w1y, fmaf(a0, w0y, bey));
                ax = fmaf(lo2f(hv[j]), ex, ax);
                ay = fmaf(hi2f(hv[j]), ey, ay);
            }
        }
        float inv = 1.0f / (float)(dg > 0 ? dg : 1);
        float tx = lo2f(hn) + ax * inv;
        float ty = hi2f(hn) + ay * inv;
        tile[i * TPAD + lane] = (uint32_t)f2bf(tx) | ((uint32_t)f2bf(ty) << 16);
        dg = dgn; st = stn;
    }
    // no barrier: single wave, own tile

    f32x4 acc[8];
#pragma unroll
    for (int c = 0; c < 8; c++) acc[c] = (f32x4){0.f, 0.f, 0.f, 0.f};

#pragma unroll
    for (int kk = 0; kk < 4; kk++) {
        bf16x8 a = *(const bf16x8*)(tile + l16 * TPAD + kk * 16 + quad * 4);
#pragma unroll
        for (int c = 0; c < 8; c++) {
            bf16x8 b = *(const bf16x8*)(WTg + (c * 16 + l16) * 128 + kk * 32 + quad * 8);
            acc[c] = __builtin_amdgcn_mfma_f32_16x16x32_bf16(a, b, acc[c], 0, 0, 0);
        }
    }
    if (!dopool) {
#pragma unroll
        for (int c = 0; c < 8; c++) {
            int gcol = c * 16 + l16;
            float s = sc[gcol], o = sh[gcol];
#pragma unroll
            for (int r = 0; r < 4; r++) {
                float v = fmaxf(fmaf(acc[c][r], s, o), 0.f);
                Hout[(size_t)(nodebase + quad * 4 + r) * 128 + gcol] = f2bf(v);
            }
        }
    } else {
        int shard = blockIdx.x & (NSHARD - 1);
        float* gs = (shard == 0) ? gsum : (gsum2 + (size_t)(shard - 1) * NG * HD);
        int bg0 = batch[nodebase];
        int bg15 = batch[nodebase + 15];
        if (bg0 == bg15) {
            // fast path: whole tile in one segment; register column-sums +
            // cross-quad shfl reduce; one atomic per column from quad 0.
#pragma unroll
            for (int c = 0; c < 8; c++) {
                int gcol = c * 16 + l16;
                float s = sc[gcol], o = sh[gcol];
                float cs = 0.f;
#pragma unroll
                for (int r = 0; r < 4; r++) {
                    float v = fmaxf(fmaf(acc[c][r], s, o), 0.f);
                    cs += bf2f(f2bf(v));
                }
                cs += __shfl_xor(cs, 16);
                cs += __shfl_xor(cs, 32);
                if (quad == 0) atomicAdd(&gs[bg0 * 128 + gcol], cs);
            }
            if (lane == 0) atomicAdd(&gcnt[bg0], 16);
        } else {
            // slow path (segment boundary): LDS staging + segment scan
#pragma unroll
            for (int c = 0; c < 8; c++) {
                int gcol = c * 16 + l16;
                float s = sc[gcol], o = sh[gcol];
#pragma unroll
                for (int r = 0; r < 4; r++) {
                    float v = fmaxf(fmaf(acc[c][r], s, o), 0.f);
                    float vb = bf2f(f2bf(v));
                    tile[(quad * 4 + r) * PPAD + gcol] = __float_as_uint(vb);
                }
            }
            int bg[16];
#pragma unroll
            for (int i = 0; i < 16; i++) bg[i] = batch[nodebase + i];
#pragma unroll
            for (int cc = 0; cc < 2; cc++) {
                int colx = lane + cc * 64;
                float s = 0.f;
                int g = bg[0];
#pragma unroll
                for (int i = 0; i < 16; i++) {
                    int gi = bg[i];
                    if (gi != g) { atomicAdd(&gs[g * 128 + colx], s); s = 0.f; g = gi; }
                    s += __uint_as_float(tile[i * PPAD + colx]);
                }
                atomicAdd(&gs[g * 128 + colx], s);
            }
            if (lane == 0) {
                int g = bg[0]; int c = 0;
#pragma unroll
                for (int i = 0; i < 16; i++) {
                    int gi = bg[i];
                    if (gi != g) { atomicAdd(&gcnt[g], c); c = 0; g = gi; }
                    c++;
                }
                atomicAdd(&gcnt[g], c);
            }
        }
    }
}

// ---------------- GEMM: h0 = x @ W_in + b_in   ([N,64]x[64,128]) -> internal bf16
// Block 0 additionally zeroes the dummy row N of both hA and hB (replaces
// two 256B memset dispatches; runs before any layer reads them).
__global__ __launch_bounds__(256) void gemm_in_k(
    const void* __restrict__ X, const void* __restrict__ W,
    const void* __restrict__ bin, ushort_t* __restrict__ Hout,
    ushort_t* __restrict__ HoutB, const int* __restrict__ flag)
{
    __shared__ ushort_t WT[128 * 72];
    int isb = flag[0];
    int tid = threadIdx.x;
    if (blockIdx.x == 0 && tid < 64) {
        ((uint32_t*)(Hout + (size_t)N_NODES * HD))[tid] = 0u;
        ((uint32_t*)(HoutB + (size_t)N_NODES * HD))[tid] = 0u;
    }
    for (int idx = tid; idx < 64 * 128; idx += 256) {
        int k = idx >> 7, n = idx & 127;
        WT[n * 72 + k] = f2bf(ldf(W, idx, isb));
    }
    __syncthreads();
    int wave = tid >> 6, lane = tid & 63;
    int quad = lane >> 4, l16 = lane & 15;
    int row = blockIdx.x * 64 + wave * 16 + l16;

    f32x4 acc[8];
#pragma unroll
    for (int c = 0; c < 8; c++) acc[c] = (f32x4){0.f, 0.f, 0.f, 0.f};

#pragma unroll
    for (int kk = 0; kk < 2; kk++) {
        int aoff = row * 64 + kk * 32 + quad * 8;
        union { bf16x8 v; ushort_t s[8]; } a;
        if (isb) {
            a.v = *(const bf16x8*)((const ushort_t*)X + aoff);
        } else {
            const float* xf = (const float*)X + aoff;
            f32x4 p0 = *(const f32x4*)xf;
            f32x4 p1 = *(const f32x4*)(xf + 4);
#pragma unroll
            for (int j = 0; j < 4; j++) { a.s[j] = f2bf(p0[j]); a.s[4 + j] = f2bf(p1[j]); }
        }
#pragma unroll
        for (int c = 0; c < 8; c++) {
            bf16x8 b = *(const bf16x8*)(&WT[(c * 16 + l16) * 72 + kk * 32 + quad * 8]);
            acc[c] = __builtin_amdgcn_mfma_f32_16x16x32_bf16(a.v, b, acc[c], 0, 0, 0);
        }
    }
    int rbase = blockIdx.x * 64 + wave * 16 + quad * 4;
#pragma unroll
    for (int c = 0; c < 8; c++) {
        int gcol = c * 16 + l16;
        float bb = ldf(bin, gcol, isb);
#pragma unroll
        for (int r = 0; r < 4; r++) {
            Hout[(rbase + r) * 128 + gcol] = f2bf(acc[c][r] + bb);
        }
    }
}

// ---------------- final: sums the 8 gsum shards
__global__ __launch_bounds__(128) void final_k(
    const float* __restrict__ gsum, const float* __restrict__ gsum2,
    const int* __restrict__ gcnt,
    const void* __restrict__ gx, const void* __restrict__ Wgp,
    const void* __restrict__ bgp, const void* __restrict__ Wgc,
    const void* __restrict__ bgc, void* __restrict__ out,
    const int* __restrict__ flag)
{
    __shared__ float gm[160];
    int isb = flag[0];
    int g = blockIdx.x, t = threadIdx.x;
    int c = gcnt[g]; if (c < 1) c = 1;
    float acc = gsum[g * 128 + t];
#pragma unroll
    for (int s = 1; s < NSHARD; s++)
        acc += gsum2[(size_t)(s - 1) * NG * HD + g * 128 + t];
    gm[t] = acc / (float)c;
    if (t < 32) {
        float a = ldf(bgp, t, isb);
        for (int d = 0; d < 6; d++) a += ldf(gx, g * 6 + d, isb) * ldf(Wgp, d * 32 + t, isb);
        gm[128 + t] = fmaxf(a, 0.f);
    }
    __syncthreads();
    float a = ldf(bgc, t, isb);
    for (int k = 0; k < 160; k++) a += gm[k] * ldf(Wgc, k * 128 + t, isb);
    if (isb) ((ushort_t*)out)[g * 128 + t] = f2bf(a);
    else     ((float*)out)[g * 128 + t] = a;
}

extern "C" void kernel_launch(void* const* d_in, const int* in_sizes, int n_in,
                              void* d_out, int out_size, void* d_ws, size_t ws_size,
                              hipStream_t stream) {
    const void* x       = d_in[0];
    const void* ea_raw  = d_in[1];
    const void* gx      = d_in[2];
    const void* W_in    = d_in[3];
    const void* b_in    = d_in[4];
    const void* W_edge  = d_in[5];
    const void* b_edge  = d_in[6];
    const void* W_gcn   = d_in[7];
    const void* b_gcn   = d_in[8];
    const void* bn_g    = d_in[9];
    const void* bn_b    = d_in[10];
    const void* bn_m    = d_in[11];
    const void* bn_v    = d_in[12];
    const void* W_gproj = d_in[13];
    const void* b_gproj = d_in[14];
    const void* W_gcomb = d_in[15];
    const void* b_gcomb = d_in[16];
    const int* row   = (const int*)d_in[17];
    const int* col   = (const int*)d_in[18];
    const int* batch = (const int*)d_in[19];

    char* ws = (char*)d_ws;
    size_t off = 0;
    float*    gsum    = (float*)(ws + off);    off += (size_t)NG * HD * 4;
    int*      gcnt    = (int*)(ws + off);      off += 256;
    size_t zero_bytes = off;                    // [gsum|gcnt]
    int*      flag    = (int*)(ws + off);      off += 256;
    uint32_t* cntmat  = (uint32_t*)(ws + off); off += 256 * 256 * 4;
    uint32_t* offmat  = (uint32_t*)(ws + off); off += 256 * 256 * 4;
    uint32_t* btot    = (uint32_t*)(ws + off); off += 1024;   // slot retained (layout frozen); unused
    uint32_t* bbase   = (uint32_t*)(ws + off); off += 1024;
    int*      csr_off = (int*)(ws + off);      off += (size_t)N_NODES * 4;
    int*      deg     = (int*)(ws + off);      off += (size_t)N_NODES * 4;
    ushort_t* wtg     = (ushort_t*)(ws + off); off += (size_t)NL * HD * HD * 2;
    float*    sc      = (float*)(ws + off);    off += (size_t)NL * HD * 4;
    float*    sh      = (float*)(ws + off);    off += (size_t)NL * HD * 4;
    uint2*    csr     = (uint2*)(ws + off);    off += (size_t)CSR_CAP * 8;
    ushort_t* hA      = (ushort_t*)(ws + off); off += (size_t)(N_NODES + 1) * HD * 2;
    ushort_t* hB      = (ushort_t*)(ws + off); off += (size_t)(N_NODES + 1) * HD * 2;
    uint2*    staged  = (uint2*)hB;  // overlay: staged (16.8MB) dead before layer0 writes hB
    // overlay: gsum shards 1..7 (224KB) on cntmat (256KB), dead after buildB
    float*    gsum2   = (float*)cntmat;
    (void)btot;

    hipMemsetAsync(ws, 0, zero_bytes, stream);
    detect_k<<<1, 256, 0, stream>>>((const uint32_t*)ea_raw, flag);
    prep_transpose_k<<<(NL * HD * HD + 255) / 256, 256, 0, stream>>>(
        bn_g, bn_b, bn_m, bn_v, b_gcn, sc, sh, W_gcn, wtg, flag);

    bucketA_k<<<NCHUNK, 1024, 0, stream>>>(row, col, ea_raw, staged, cntmat, offmat, flag);
    bsumscan_k<<<1, 256, 0, stream>>>(cntmat, bbase);
    buildB_k<<<BUCKETS, 1024, 0, stream>>>(staged, cntmat, offmat, bbase, csr, csr_off, deg);
    // cntmat dead; zero the shard overlay before the pooling layer runs
    hipMemsetAsync(gsum2, 0, (size_t)(NSHARD - 1) * NG * HD * 4, stream);

    gemm_in_k<<<N_NODES / 64, 256, 0, stream>>>(x, W_in, b_in, hA, hB, flag);

    ushort_t* hin = hA;
    ushort_t* hout = hB;
    for (int l = 0; l < NL; l++) {
        layer_fused_k<<<N_NODES / 16, 64, 0, stream>>>(
            (const uint32_t*)hin, csr_off, deg, csr,
            W_edge, b_edge, wtg + (size_t)l * HD * HD, sc + l * HD, sh + l * HD,
            hout, gsum, gsum2, gcnt, batch, (l == NL - 1) ? 1 : 0, flag);
        ushort_t* tmp = hin; hin = hout; hout = tmp;
    }

    final_k<<<NG, 128, 0, stream>>>(gsum, gsum2, gcnt, gx, W_gproj, b_gproj,
                                    W_gcomb, b_gcomb, d_out, flag);
}